// Round 6
// baseline (584.091 us; speedup 1.0000x reference)
//
#include <hip/hip_runtime.h>

typedef unsigned short u16;
typedef unsigned int u32;
typedef __attribute__((ext_vector_type(8))) short bf16x8;   // 8 bf16 = 4 VGPRs (MFMA A/B frag)
typedef __attribute__((ext_vector_type(4))) float f32x4;    // MFMA C/D frag

__device__ __forceinline__ u16 f2bf(float f) {
    u32 u = __float_as_uint(f);
    return (u16)((u + 0x7FFFu + ((u >> 16) & 1u)) >> 16);   // round-to-nearest-even
}
// XOR swizzle for 128x128 bf16 tile stored as uint4[2048]: row r (0..127), 16B-chunk c (0..15)
__device__ __forceinline__ int sw_idx(int r, int c) { return r * 16 + (c ^ (r & 15)); }

// fast GELU: tanh approximation (~12 VALU inst; |err| vs exact erf-gelu ~3e-3)
__device__ __forceinline__ float fast_gelu(float x) {
    const float x3 = x * x * x;
    const float y2 = 1.5957691216057308f * (x + 0.044715f * x3);   // 2*0.79788456*(x+c x^3)
    const float u = __expf(fminf(y2, 80.f));                        // e^{2y}, overflow-capped
    const float th = (u - 1.f) / (u + 1.f);                         // tanh(y)
    return 0.5f * x * (1.f + th);
}

// ---------------------------------------------------------------------------
// Prep: cast fp32 -> bf16 streaming (feats / dw_w)
// ---------------------------------------------------------------------------
__global__ __launch_bounds__(256) void cast_feats_k(
    const float* __restrict__ src, u16* __restrict__ dst, int n4)
{
    const int e = blockIdx.x * 256 + threadIdx.x;
    if (e >= n4) return;
    const float4 v = *(const float4*)(src + (size_t)e * 4);
    uint2 o;
    o.x = (u32)f2bf(v.x) | ((u32)f2bf(v.y) << 16);
    o.y = (u32)f2bf(v.z) | ((u32)f2bf(v.w) << 16);
    *(uint2*)(dst + (size_t)e * 4) = o;
}

// ---------------------------------------------------------------------------
// Kernel A: sparse depthwise conv + bias + LayerNorm.
// 1 wave/site; upfront idx loads; VALU compaction; 8-deep gather batching.
// ---------------------------------------------------------------------------
__global__ __launch_bounds__(256) void dwln_k(
    const u16* __restrict__ featsb, const int* __restrict__ nb,
    const u16* __restrict__ dwwb, const float* __restrict__ dw_b,
    const float* __restrict__ ln_g, const float* __restrict__ ln_b,
    u16* __restrict__ xln, int nsites)
{
    __shared__ int lists[4][348];
    const int w = threadIdx.x >> 6;
    const int lane = threadIdx.x & 63;
    const int site = blockIdx.x * 4 + w;
    if (site >= nsites) return;
    const int* row = nb + (size_t)site * 343;
    int idxs[6];
    #pragma unroll
    for (int j = 0; j < 5; ++j) idxs[j] = row[lane + j * 64];
    idxs[5] = (lane < 23) ? row[320 + lane] : nsites;
    int c = 0;
    #pragma unroll
    for (int i = 0; i < 6; ++i) c += (idxs[i] < nsites) ? 1 : 0;
    int pre = c;
    #pragma unroll
    for (int off = 1; off < 64; off <<= 1) {
        const int v = __shfl_up(pre, off, 64);
        if (lane >= off) pre += v;
    }
    const int cnt = __shfl(pre, 63, 64);
    pre -= c;
    #pragma unroll
    for (int i = 0; i < 6; ++i) {
        if (idxs[i] < nsites) {
            lists[w][pre++] = idxs[i] | ((lane + i * 64) << 17);
        }
    }
    float a0 = 0.f, a1 = 0.f;
    for (int base = 0; base < cnt; base += 8) {
        u32 fv[8], wv[8];
        const int mlen = cnt - base;
        #pragma unroll
        for (int i = 0; i < 8; ++i) {
            if (i < mlen) {
                const int p = lists[w][base + i];
                fv[i] = *(const u32*)(featsb + (size_t)(p & 0x1FFFF) * 128 + lane * 2);
                wv[i] = *(const u32*)(dwwb + (size_t)(p >> 17) * 128 + lane * 2);
            } else { fv[i] = 0u; wv[i] = 0u; }
        }
        #pragma unroll
        for (int i = 0; i < 8; ++i) {
            const float f0 = __uint_as_float(fv[i] << 16);
            const float f1 = __uint_as_float(fv[i] & 0xFFFF0000u);
            const float g0 = __uint_as_float(wv[i] << 16);
            const float g1 = __uint_as_float(wv[i] & 0xFFFF0000u);
            a0 += f0 * g0;
            a1 += f1 * g1;
        }
    }
    const float2 bv = *(const float2*)(dw_b + lane * 2);
    a0 += bv.x;
    a1 += bv.y;
    float s = a0 + a1, ss = a0 * a0 + a1 * a1;
    #pragma unroll
    for (int off = 32; off > 0; off >>= 1) {
        s += __shfl_xor(s, off, 64);
        ss += __shfl_xor(ss, off, 64);
    }
    const float mean = s * (1.f / 128.f);
    const float var = ss * (1.f / 128.f) - mean * mean;
    const float rstd = rsqrtf(fmaxf(var, 0.f) + 1e-6f);
    const float2 gv = *(const float2*)(ln_g + lane * 2);
    const float2 lbv = *(const float2*)(ln_b + lane * 2);
    const float y0 = (a0 - mean) * rstd * gv.x + lbv.x;
    const float y1 = (a1 - mean) * rstd * gv.y + lbv.y;
    *(u32*)(xln + (size_t)site * 128 + lane * 2) = (u32)f2bf(y0) | ((u32)f2bf(y1) << 16);
}

// ---------------------------------------------------------------------------
// w1 fp32 [128,512] -> w1t bf16 [512,128] (B^T layout for MFMA B-frag reads)
// ---------------------------------------------------------------------------
__global__ __launch_bounds__(256) void transpose_w1_k(
    const float* __restrict__ w1, u16* __restrict__ w1t)
{
    const int e = blockIdx.x * 256 + threadIdx.x;    // 65536 total
    const int n = e >> 7, k = e & 127;
    w1t[e] = f2bf(w1[k * 512 + n]);
}

// ---------------------------------------------------------------------------
// Kernel B: Σ_h per-channel sum(h^2) ONLY, h = gelu(xln @ w1 + b1).
// h is NOT written (fused_k recomputes it). A staged once in 32 KB LDS;
// B frags from L2-resident w1t.
// ---------------------------------------------------------------------------
__global__ __launch_bounds__(256, 3) void gemm1sq_k(
    const u16* __restrict__ xln, const u16* __restrict__ w1t,
    const float* __restrict__ b1, float* __restrict__ gx_sq, int nsites)
{
    __shared__ uint4 sA[2048];   // 32 KB
    __shared__ float s_red[512];
    const int t = threadIdx.x;
    const int m0 = blockIdx.x * 128;
    #pragma unroll
    for (int it = 0; it < 8; ++it) {
        const int e = it * 256 + t;
        const int r = e >> 4, c = e & 15;
        uint4 va = {0u, 0u, 0u, 0u};
        const int rowg = m0 + r;
        if (rowg < nsites) va = *(const uint4*)(xln + (size_t)rowg * 128 + c * 8);
        sA[sw_idx(r, c)] = va;
    }
    s_red[t] = 0.f;
    s_red[t + 256] = 0.f;
    __syncthreads();
    const int lane = t & 63;
    const int w = t >> 6;
    const int wm = (w >> 1) * 64, wn = (w & 1) * 64;
    const int l15 = lane & 15, quad = lane >> 4;
    for (int j = 0; j < 4; ++j) {
        const int n0 = j * 128;
        f32x4 acc[4][4];
        #pragma unroll
        for (int i = 0; i < 4; ++i)
            #pragma unroll
            for (int jj = 0; jj < 4; ++jj) acc[i][jj] = f32x4{0.f, 0.f, 0.f, 0.f};
        #pragma unroll
        for (int ks = 0; ks < 4; ++ks) {
            const int cq = ks * 4 + quad;
            bf16x8 a[4], b[4];
            #pragma unroll
            for (int mt = 0; mt < 4; ++mt) a[mt] = *(const bf16x8*)&sA[sw_idx(wm + mt * 16 + l15, cq)];
            #pragma unroll
            for (int nt = 0; nt < 4; ++nt)
                b[nt] = *(const bf16x8*)(w1t + (size_t)(n0 + wn + nt * 16 + l15) * 128 + cq * 8);
            #pragma unroll
            for (int mt = 0; mt < 4; ++mt)
                #pragma unroll
                for (int nt = 0; nt < 4; ++nt)
                    acc[mt][nt] = __builtin_amdgcn_mfma_f32_16x16x32_bf16(a[mt], b[nt], acc[mt][nt], 0, 0, 0);
        }
        float ssl[4] = {0.f, 0.f, 0.f, 0.f};
        float bias[4]; int col[4];
        #pragma unroll
        for (int nt = 0; nt < 4; ++nt) {
            col[nt] = n0 + wn + nt * 16 + l15;
            bias[nt] = b1[col[nt]];
        }
        #pragma unroll
        for (int mt = 0; mt < 4; ++mt) {
            const int rbase = m0 + wm + mt * 16 + quad * 4;
            #pragma unroll
            for (int nt = 0; nt < 4; ++nt) {
                #pragma unroll
                for (int rg = 0; rg < 4; ++rg) {
                    if (rbase + rg < nsites) {
                        const float v = fast_gelu(acc[mt][nt][rg] + bias[nt]);
                        ssl[nt] += v * v;
                    }
                }
            }
        }
        #pragma unroll
        for (int nt = 0; nt < 4; ++nt) atomicAdd(&s_red[col[nt]], ssl[nt]);
    }
    __syncthreads();
    atomicAdd(&gx_sq[t], s_red[t]);
    atomicAdd(&gx_sq[t + 256], s_red[t + 256]);
}

// ---------------------------------------------------------------------------
// Kernel C1: GRN scale + effective bias (one block, cooperative).
// ---------------------------------------------------------------------------
__global__ __launch_bounds__(512) void grn_scale_k(
    const float* __restrict__ gx_sq, const float* __restrict__ grn_g,
    const float* __restrict__ grn_b, const float* __restrict__ w2,
    const float* __restrict__ b2, float* __restrict__ scale, float* __restrict__ b_eff)
{
    __shared__ float red[512];
    __shared__ float redb[512];
    const int t = threadIdx.x;
    const float g = sqrtf(gx_sq[t]);
    red[t] = g;
    __syncthreads();
    #pragma unroll
    for (int off = 256; off > 0; off >>= 1) {
        if (t < off) red[t] += red[t + off];
        __syncthreads();
    }
    const float mean = red[0] * (1.f / 512.f);
    scale[t] = grn_g[t] * (g / (mean + 1e-6f)) + 1.f;
    const int dc = t & 127, grp = t >> 7;
    float p = 0.f;
    #pragma unroll 8
    for (int i = 0; i < 128; ++i) {
        const int c = grp * 128 + i;
        p += grn_b[c] * w2[(size_t)c * 128 + dc];
    }
    redb[t] = p;
    __syncthreads();
    if (t < 128) b_eff[t] = b2[t] + redb[t] + redb[t + 128] + redb[t + 256] + redb[t + 384];
}

// ---------------------------------------------------------------------------
// Kernel C2: w2t[dc][c] = bf16(scale[c] * w2[c][dc])  (coalesced writes)
// ---------------------------------------------------------------------------
__global__ __launch_bounds__(256) void w2t_k(
    const float* __restrict__ scale, const float* __restrict__ w2,
    u16* __restrict__ w2t)
{
    const int e = blockIdx.x * 256 + threadIdx.x;    // 65536
    const int c = e & 511, dc = e >> 9;
    w2t[e] = f2bf(scale[c] * w2[(size_t)c * 128 + dc]);
}

// ---------------------------------------------------------------------------
// Kernel D (fused): out = feats + gelu(xln@w1+b1) @ w2t_scaled + b_eff.
// Per 128-row tile: stage xln in LDS once; for each 128-col chunk j:
//   (1) acc1 = xln_tile @ w1t[:,j]  (MFMA)  -> gelu -> bf16 -> swizzled LDS
//   (2) acc2 += hchunk(LDS, A-layout reads) @ w2t[:, jchunk]  (MFMA)
// h never touches HBM. LDS = 32+32 KB -> 2 blocks/CU.
// ---------------------------------------------------------------------------
__global__ __launch_bounds__(256) void fused_k(
    const u16* __restrict__ xln, const u16* __restrict__ w1t,
    const float* __restrict__ b1, const u16* __restrict__ w2t,
    const float* __restrict__ b_eff, const float* __restrict__ feats,
    float* __restrict__ out, int nsites)
{
    __shared__ uint4 sX[2048];   // 32 KB: xln tile (swizzled)
    __shared__ uint4 sH[2048];   // 32 KB: current h chunk (swizzled)
    const int t = threadIdx.x;
    const int m0 = blockIdx.x * 128;
    #pragma unroll
    for (int it = 0; it < 8; ++it) {
        const int e = it * 256 + t;
        const int r = e >> 4, c = e & 15;
        uint4 va = {0u, 0u, 0u, 0u};
        const int rowg = m0 + r;
        if (rowg < nsites) va = *(const uint4*)(xln + (size_t)rowg * 128 + c * 8);
        sX[sw_idx(r, c)] = va;
    }
    __syncthreads();
    const int lane = t & 63;
    const int w = t >> 6;
    const int wm = (w >> 1) * 64, wn = (w & 1) * 64;
    const int l15 = lane & 15, quad = lane >> 4;
    f32x4 acc2[4][4];
    #pragma unroll
    for (int i = 0; i < 4; ++i)
        #pragma unroll
        for (int j = 0; j < 4; ++j) acc2[i][j] = f32x4{0.f, 0.f, 0.f, 0.f};
    u16* sHh = (u16*)sH;
    for (int j = 0; j < 4; ++j) {
        const int n0 = j * 128;
        // ---- phase 1: h chunk = gelu(xln_tile @ w1t[n0:n0+128] + b1) ----
        f32x4 acc1[4][4];
        #pragma unroll
        for (int i = 0; i < 4; ++i)
            #pragma unroll
            for (int jj = 0; jj < 4; ++jj) acc1[i][jj] = f32x4{0.f, 0.f, 0.f, 0.f};
        #pragma unroll
        for (int ks = 0; ks < 4; ++ks) {
            const int cq = ks * 4 + quad;
            bf16x8 a[4], b[4];
            #pragma unroll
            for (int mt = 0; mt < 4; ++mt) a[mt] = *(const bf16x8*)&sX[sw_idx(wm + mt * 16 + l15, cq)];
            #pragma unroll
            for (int nt = 0; nt < 4; ++nt)
                b[nt] = *(const bf16x8*)(w1t + (size_t)(n0 + wn + nt * 16 + l15) * 128 + cq * 8);
            #pragma unroll
            for (int mt = 0; mt < 4; ++mt)
                #pragma unroll
                for (int nt = 0; nt < 4; ++nt)
                    acc1[mt][nt] = __builtin_amdgcn_mfma_f32_16x16x32_bf16(a[mt], b[nt], acc1[mt][nt], 0, 0, 0);
        }
        if (j) __syncthreads();             // prior chunk's sH reads complete
        float bias[4];
        #pragma unroll
        for (int nt = 0; nt < 4; ++nt) bias[nt] = b1[n0 + wn + nt * 16 + l15];
        #pragma unroll
        for (int mt = 0; mt < 4; ++mt) {
            const int rloc = wm + mt * 16 + quad * 4;   // tile-local row
            #pragma unroll
            for (int nt = 0; nt < 4; ++nt) {
                const int cloc = wn + nt * 16 + l15;    // chunk-local col
                const int cc = cloc >> 3, cw = cloc & 7;
                #pragma unroll
                for (int rg = 0; rg < 4; ++rg) {
                    const float v = fast_gelu(acc1[mt][nt][rg] + bias[nt]);
                    sHh[sw_idx(rloc + rg, cc) * 8 + cw] = f2bf(v);
                }
            }
        }
        __syncthreads();
        // ---- phase 2: acc2 += h_chunk @ w2t[:, n0:n0+128] ----
        #pragma unroll
        for (int ks = 0; ks < 4; ++ks) {
            const int cq = ks * 4 + quad;
            bf16x8 a[4], b[4];
            #pragma unroll
            for (int mt = 0; mt < 4; ++mt) a[mt] = *(const bf16x8*)&sH[sw_idx(wm + mt * 16 + l15, cq)];
            #pragma unroll
            for (int nt = 0; nt < 4; ++nt)
                b[nt] = *(const bf16x8*)(w2t + (size_t)(wn + nt * 16 + l15) * 512 + n0 + cq * 8);
            #pragma unroll
            for (int mt = 0; mt < 4; ++mt)
                #pragma unroll
                for (int nt = 0; nt < 4; ++nt)
                    acc2[mt][nt] = __builtin_amdgcn_mfma_f32_16x16x32_bf16(a[mt], b[nt], acc2[mt][nt], 0, 0, 0);
        }
    }
    float be[4]; int col[4];
    #pragma unroll
    for (int nt = 0; nt < 4; ++nt) {
        col[nt] = wn + nt * 16 + l15;
        be[nt] = b_eff[col[nt]];
    }
    #pragma unroll
    for (int mt = 0; mt < 4; ++mt) {
        const int rbase = m0 + wm + mt * 16 + quad * 4;
        #pragma unroll
        for (int nt = 0; nt < 4; ++nt) {
            #pragma unroll
            for (int rg = 0; rg < 4; ++rg) {
                const int rowg = rbase + rg;
                if (rowg < nsites) {
                    out[(size_t)rowg * 128 + col[nt]] =
                        acc2[mt][nt][rg] + be[nt] + feats[(size_t)rowg * 128 + col[nt]];
                }
            }
        }
    }
}

// ---------------------------------------------------------------------------
extern "C" void kernel_launch(void* const* d_in, const int* in_sizes, int n_in,
                              void* d_out, int out_size, void* d_ws, size_t ws_size,
                              hipStream_t stream) {
    const float* feats = (const float*)d_in[0];    // [N,128] f32
    const int* nb      = (const int*)d_in[1];      // [N,343] int32
    const float* dw_w  = (const float*)d_in[2];    // [343,128] f32
    const float* dw_b  = (const float*)d_in[3];    // [128]
    const float* ln_g  = (const float*)d_in[4];    // [128]
    const float* ln_b  = (const float*)d_in[5];    // [128]
    const float* w1    = (const float*)d_in[6];    // [128,512]
    const float* b1    = (const float*)d_in[7];    // [512]
    const float* grn_g = (const float*)d_in[8];    // [512]
    const float* grn_b = (const float*)d_in[9];    // [512]
    const float* w2    = (const float*)d_in[10];   // [512,128]
    const float* b2    = (const float*)d_in[11];   // [128]
    float* out = (float*)d_out;
    const int nsites = in_sizes[0] / 128;

    char* ws = (char*)d_ws;
    size_t off = 0;
    u16* xln   = (u16*)(ws + off);  off += (((size_t)nsites * 128 * 2) + 255) & ~(size_t)255;
    u16* featsb= (u16*)(ws + off);  off += (((size_t)nsites * 128 * 2) + 255) & ~(size_t)255;
    u16* dwwb  = (u16*)(ws + off);  off += 343 * 128 * 2 + 128;
    u16* w1t   = (u16*)(ws + off);  off += 512 * 128 * 2;
    u16* w2t   = (u16*)(ws + off);  off += 128 * 512 * 2;
    float* gx_sq = (float*)(ws + off); off += 512 * 4;
    float* scale = (float*)(ws + off); off += 512 * 4;
    float* b_eff = (float*)(ws + off); off += 128 * 4;

    hipMemsetAsync(gx_sq, 0, 512 * sizeof(float), stream);
    const int nfeat4 = nsites * 32;
    cast_feats_k<<<(nfeat4 + 255) / 256, 256, 0, stream>>>(feats, featsb, nfeat4);
    const int ndww4 = 343 * 32;
    cast_feats_k<<<(ndww4 + 255) / 256, 256, 0, stream>>>(dw_w, dwwb, ndww4);
    transpose_w1_k<<<256, 256, 0, stream>>>(w1, w1t);
    dwln_k<<<(nsites + 3) / 4, 256, 0, stream>>>(featsb, nb, dwwb, dw_b, ln_g, ln_b, xln, nsites);
    const int mblocks = (nsites + 127) / 128;
    gemm1sq_k<<<mblocks, 256, 0, stream>>>(xln, w1t, b1, gx_sq, nsites);
    grn_scale_k<<<1, 512, 0, stream>>>(gx_sq, grn_g, grn_b, w2, b2, scale, b_eff);
    w2t_k<<<256, 256, 0, stream>>>(scale, w2, w2t);
    fused_k<<<mblocks, 256, 0, stream>>>(xln, w1t, b1, w2t, b_eff, feats, out, nsites);
}

// Round 7
// 517.164 us; speedup vs baseline: 1.1294x; 1.1294x over previous
//
#include <hip/hip_runtime.h>

typedef unsigned short u16;
typedef unsigned int u32;
typedef __attribute__((ext_vector_type(8))) short bf16x8;   // 8 bf16 = 4 VGPRs (MFMA A/B frag)
typedef __attribute__((ext_vector_type(4))) float f32x4;    // MFMA C/D frag

__device__ __forceinline__ u16 f2bf(float f) {
    u32 u = __float_as_uint(f);
    return (u16)((u + 0x7FFFu + ((u >> 16) & 1u)) >> 16);   // round-to-nearest-even
}
// XOR swizzle for 128x128 bf16 tile stored as uint4[2048]: row r (0..127), 16B-chunk c (0..15)
__device__ __forceinline__ int sw_idx(int r, int c) { return r * 16 + (c ^ (r & 15)); }

// fast GELU: tanh approximation (~12 VALU inst; |err| vs exact erf-gelu ~3e-3)
__device__ __forceinline__ float fast_gelu(float x) {
    const float x3 = x * x * x;
    const float y2 = 1.5957691216057308f * (x + 0.044715f * x3);   // 2*0.79788456*(x+c x^3)
    const float u = __expf(fminf(y2, 80.f));                        // e^{2y}, overflow-capped
    const float th = (u - 1.f) / (u + 1.f);                         // tanh(y)
    return 0.5f * x * (1.f + th);
}

// ---------------------------------------------------------------------------
// Prep: cast fp32 -> bf16 streaming (feats / dw_w)
// ---------------------------------------------------------------------------
__global__ __launch_bounds__(256) void cast_feats_k(
    const float* __restrict__ src, u16* __restrict__ dst, int n4)
{
    const int e = blockIdx.x * 256 + threadIdx.x;
    if (e >= n4) return;
    const float4 v = *(const float4*)(src + (size_t)e * 4);
    uint2 o;
    o.x = (u32)f2bf(v.x) | ((u32)f2bf(v.y) << 16);
    o.y = (u32)f2bf(v.z) | ((u32)f2bf(v.w) << 16);
    *(uint2*)(dst + (size_t)e * 4) = o;
}

// ---------------------------------------------------------------------------
// Kernel A: sparse depthwise conv + bias + LayerNorm.  TWO sites per wave:
// packed dual prefix-sum compaction (one shuffle chain), interleaved gather
// streams (2x independent load chains), two LN epilogues.
// ---------------------------------------------------------------------------
__global__ __launch_bounds__(256) void dwln_k(
    const u16* __restrict__ featsb, const int* __restrict__ nb,
    const u16* __restrict__ dwwb, const float* __restrict__ dw_b,
    const float* __restrict__ ln_g, const float* __restrict__ ln_b,
    u16* __restrict__ xln, int nsites)
{
    __shared__ int lists[8][348];
    const int w = threadIdx.x >> 6;
    const int lane = threadIdx.x & 63;
    const int s0 = blockIdx.x * 8 + w * 2;
    if (s0 >= nsites) return;
    const bool two = (s0 + 1) < nsites;
    const int* rowA = nb + (size_t)s0 * 343;
    const int* rowB = nb + (size_t)(two ? s0 + 1 : s0) * 343;
    int idxA[6], idxB[6];
    #pragma unroll
    for (int j = 0; j < 5; ++j) {
        idxA[j] = rowA[lane + j * 64];
        const int vb = rowB[lane + j * 64];
        idxB[j] = two ? vb : nsites;
    }
    idxA[5] = (lane < 23) ? rowA[320 + lane] : nsites;
    idxB[5] = (two && lane < 23) ? rowB[320 + lane] : nsites;
    int cA = 0, cB = 0;
    #pragma unroll
    for (int i = 0; i < 6; ++i) {
        cA += (idxA[i] < nsites) ? 1 : 0;
        cB += (idxB[i] < nsites) ? 1 : 0;
    }
    // packed dual prefix-sum (counts fit in 16 bits)
    const int packed = cA | (cB << 16);
    int pre = packed;
    #pragma unroll
    for (int off = 1; off < 64; off <<= 1) {
        const int v = __shfl_up(pre, off, 64);
        if (lane >= off) pre += v;
    }
    const int tot = __shfl(pre, 63, 64);
    const int cntA = tot & 0xFFFF, cntB = tot >> 16;
    pre -= packed;
    int pA = pre & 0xFFFF, pB = pre >> 16;
    #pragma unroll
    for (int i = 0; i < 6; ++i) {
        const int k = (i < 5) ? (lane + i * 64) : (320 + lane);
        if (idxA[i] < nsites) lists[w * 2][pA++] = idxA[i] | (k << 17);
        if (idxB[i] < nsites) lists[w * 2 + 1][pB++] = idxB[i] | (k << 17);
    }
    // interleaved gather: 4-deep per site, 16 loads in flight across 2 chains
    float xA0 = 0.f, xA1 = 0.f, xB0 = 0.f, xB1 = 0.f;
    const int mx = (cntA > cntB) ? cntA : cntB;
    for (int base = 0; base < mx; base += 4) {
        u32 fa[4], wa[4], fb[4], wb[4];
        #pragma unroll
        for (int i = 0; i < 4; ++i) {
            if (base + i < cntA) {
                const int p = lists[w * 2][base + i];
                fa[i] = *(const u32*)(featsb + (size_t)(p & 0x1FFFF) * 128 + lane * 2);
                wa[i] = *(const u32*)(dwwb + (size_t)(p >> 17) * 128 + lane * 2);
            } else { fa[i] = 0u; wa[i] = 0u; }
            if (base + i < cntB) {
                const int p = lists[w * 2 + 1][base + i];
                fb[i] = *(const u32*)(featsb + (size_t)(p & 0x1FFFF) * 128 + lane * 2);
                wb[i] = *(const u32*)(dwwb + (size_t)(p >> 17) * 128 + lane * 2);
            } else { fb[i] = 0u; wb[i] = 0u; }
        }
        #pragma unroll
        for (int i = 0; i < 4; ++i) {
            xA0 += __uint_as_float(fa[i] << 16) * __uint_as_float(wa[i] << 16);
            xA1 += __uint_as_float(fa[i] & 0xFFFF0000u) * __uint_as_float(wa[i] & 0xFFFF0000u);
            xB0 += __uint_as_float(fb[i] << 16) * __uint_as_float(wb[i] << 16);
            xB1 += __uint_as_float(fb[i] & 0xFFFF0000u) * __uint_as_float(wb[i] & 0xFFFF0000u);
        }
    }
    const float2 bv = *(const float2*)(dw_b + lane * 2);
    const float2 gv = *(const float2*)(ln_g + lane * 2);
    const float2 lbv = *(const float2*)(ln_b + lane * 2);
    // LN epilogue for each site
    #pragma unroll
    for (int sidx = 0; sidx < 2; ++sidx) {
        if (sidx == 1 && !two) break;
        float a0 = (sidx == 0) ? xA0 : xB0;
        float a1 = (sidx == 0) ? xA1 : xB1;
        a0 += bv.x; a1 += bv.y;
        float s = a0 + a1, ss = a0 * a0 + a1 * a1;
        #pragma unroll
        for (int off = 32; off > 0; off >>= 1) {
            s += __shfl_xor(s, off, 64);
            ss += __shfl_xor(ss, off, 64);
        }
        const float mean = s * (1.f / 128.f);
        const float var = ss * (1.f / 128.f) - mean * mean;
        const float rstd = rsqrtf(fmaxf(var, 0.f) + 1e-6f);
        const float y0 = (a0 - mean) * rstd * gv.x + lbv.x;
        const float y1 = (a1 - mean) * rstd * gv.y + lbv.y;
        *(u32*)(xln + (size_t)(s0 + sidx) * 128 + lane * 2) =
            (u32)f2bf(y0) | ((u32)f2bf(y1) << 16);
    }
}

// ---------------------------------------------------------------------------
// w1 fp32 [128,512] -> w1t bf16 [512,128] (B^T layout for MFMA B-frag reads)
// ---------------------------------------------------------------------------
__global__ __launch_bounds__(256) void transpose_w1_k(
    const float* __restrict__ w1, u16* __restrict__ w1t)
{
    const int e = blockIdx.x * 256 + threadIdx.x;    // 65536 total
    const int n = e >> 7, k = e & 127;
    w1t[e] = f2bf(w1[k * 512 + n]);
}

// ---------------------------------------------------------------------------
// Kernel B: h = gelu(xln @ w1 + b1) [N,512] bf16 + per-channel sum(h^2).
// Grid (mb, 4): one 128x128 output tile per block -> 3128 blocks, LDS
// 32.5 KB -> 4 blocks/CU (16 waves/CU). B frags from L2-hot w1t.
// ---------------------------------------------------------------------------
__global__ __launch_bounds__(256) void gemm1_k(
    const u16* __restrict__ xln, const u16* __restrict__ w1t,
    const float* __restrict__ b1, u16* __restrict__ h,
    float* __restrict__ gx_sq, int nsites)
{
    __shared__ uint4 sA[2048];   // 32 KB
    __shared__ float s_red[128];
    const int t = threadIdx.x;
    const int m0 = blockIdx.x * 128;
    const int n0 = blockIdx.y * 128;
    #pragma unroll
    for (int it = 0; it < 8; ++it) {
        const int e = it * 256 + t;
        const int r = e >> 4, c = e & 15;
        uint4 va = {0u, 0u, 0u, 0u};
        const int rowg = m0 + r;
        if (rowg < nsites) va = *(const uint4*)(xln + (size_t)rowg * 128 + c * 8);
        sA[sw_idx(r, c)] = va;
    }
    if (t < 128) s_red[t] = 0.f;
    __syncthreads();
    const int lane = t & 63;
    const int w = t >> 6;
    const int wm = (w >> 1) * 64, wn = (w & 1) * 64;
    const int l15 = lane & 15, quad = lane >> 4;
    f32x4 acc[4][4];
    #pragma unroll
    for (int i = 0; i < 4; ++i)
        #pragma unroll
        for (int j = 0; j < 4; ++j) acc[i][j] = f32x4{0.f, 0.f, 0.f, 0.f};
    #pragma unroll
    for (int ks = 0; ks < 4; ++ks) {
        const int cq = ks * 4 + quad;
        bf16x8 a[4], b[4];
        #pragma unroll
        for (int mt = 0; mt < 4; ++mt) a[mt] = *(const bf16x8*)&sA[sw_idx(wm + mt * 16 + l15, cq)];
        #pragma unroll
        for (int nt = 0; nt < 4; ++nt)
            b[nt] = *(const bf16x8*)(w1t + (size_t)(n0 + wn + nt * 16 + l15) * 128 + cq * 8);
        #pragma unroll
        for (int mt = 0; mt < 4; ++mt)
            #pragma unroll
            for (int nt = 0; nt < 4; ++nt)
                acc[mt][nt] = __builtin_amdgcn_mfma_f32_16x16x32_bf16(a[mt], b[nt], acc[mt][nt], 0, 0, 0);
    }
    float ssl[4] = {0.f, 0.f, 0.f, 0.f};
    float bias[4]; int colg[4];
    #pragma unroll
    for (int nt = 0; nt < 4; ++nt) {
        colg[nt] = n0 + wn + nt * 16 + l15;
        bias[nt] = b1[colg[nt]];
    }
    #pragma unroll
    for (int mt = 0; mt < 4; ++mt) {
        const int rbase = m0 + wm + mt * 16 + quad * 4;
        #pragma unroll
        for (int nt = 0; nt < 4; ++nt) {
            #pragma unroll
            for (int rg = 0; rg < 4; ++rg) {
                const int rowg = rbase + rg;
                if (rowg < nsites) {
                    const float v = fast_gelu(acc[mt][nt][rg] + bias[nt]);
                    h[(size_t)rowg * 512 + colg[nt]] = f2bf(v);
                    ssl[nt] += v * v;
                }
            }
        }
    }
    #pragma unroll
    for (int nt = 0; nt < 4; ++nt) atomicAdd(&s_red[wn + nt * 16 + l15], ssl[nt]);
    __syncthreads();
    if (t < 128) atomicAdd(&gx_sq[n0 + t], s_red[t]);
}

// ---------------------------------------------------------------------------
// Kernel C1: GRN scale + effective bias (one block, cooperative).
// ---------------------------------------------------------------------------
__global__ __launch_bounds__(512) void grn_scale_k(
    const float* __restrict__ gx_sq, const float* __restrict__ grn_g,
    const float* __restrict__ grn_b, const float* __restrict__ w2,
    const float* __restrict__ b2, float* __restrict__ scale, float* __restrict__ b_eff)
{
    __shared__ float red[512];
    __shared__ float redb[512];
    const int t = threadIdx.x;
    const float g = sqrtf(gx_sq[t]);
    red[t] = g;
    __syncthreads();
    #pragma unroll
    for (int off = 256; off > 0; off >>= 1) {
        if (t < off) red[t] += red[t + off];
        __syncthreads();
    }
    const float mean = red[0] * (1.f / 512.f);
    scale[t] = grn_g[t] * (g / (mean + 1e-6f)) + 1.f;
    const int dc = t & 127, grp = t >> 7;
    float p = 0.f;
    #pragma unroll 8
    for (int i = 0; i < 128; ++i) {
        const int c = grp * 128 + i;
        p += grn_b[c] * w2[(size_t)c * 128 + dc];
    }
    redb[t] = p;
    __syncthreads();
    if (t < 128) b_eff[t] = b2[t] + redb[t] + redb[t + 128] + redb[t + 256] + redb[t + 384];
}

// ---------------------------------------------------------------------------
// Kernel C2: w2t[dc][c] = bf16(scale[c] * w2[c][dc])  (coalesced writes)
// ---------------------------------------------------------------------------
__global__ __launch_bounds__(256) void w2t_k(
    const float* __restrict__ scale, const float* __restrict__ w2,
    u16* __restrict__ w2t)
{
    const int e = blockIdx.x * 256 + threadIdx.x;    // 65536
    const int c = e & 511, dc = e >> 9;
    w2t[e] = f2bf(scale[c] * w2[(size_t)c * 128 + dc]);
}

// ---------------------------------------------------------------------------
// Kernel D: out = feats + h_scaled @ w2 + b_eff (fp32 out).
// M-tile 64 -> 1564 blocks (6/CU), NO LDS/barriers. Wave w computes rows
// m0..m0+63, cols w*32..w*32+31 (acc[4][2]). K=512 fully unrolled; A streams
// h (line-perfect frag loads), B from L2-hot w2t.
// ---------------------------------------------------------------------------
__global__ __launch_bounds__(256, 4) void gemm2_k(
    const u16* __restrict__ h, const u16* __restrict__ w2t,
    const float* __restrict__ b_eff, const float* __restrict__ feats,
    float* __restrict__ out, int nsites)
{
    const int t = threadIdx.x;
    const int m0 = blockIdx.x * 64;
    const int lane = t & 63;
    const int w = t >> 6;
    const int wn = w * 32;
    const int l15 = lane & 15, quad = lane >> 4;
    f32x4 acc[4][2];
    #pragma unroll
    for (int i = 0; i < 4; ++i)
        #pragma unroll
        for (int j = 0; j < 2; ++j) acc[i][j] = f32x4{0.f, 0.f, 0.f, 0.f};
    const u16* a_base = h + (size_t)(m0 + l15) * 512 + quad * 8;
    const u16* b_base = w2t + (size_t)(wn + l15) * 512 + quad * 8;
    #pragma unroll
    for (int ks = 0; ks < 16; ++ks) {
        const int koff = ks * 32;
        bf16x8 a[4], b[2];
        #pragma unroll
        for (int mt = 0; mt < 4; ++mt)
            a[mt] = *(const bf16x8*)(a_base + (size_t)mt * 16 * 512 + koff);
        #pragma unroll
        for (int nt = 0; nt < 2; ++nt)
            b[nt] = *(const bf16x8*)(b_base + (size_t)nt * 16 * 512 + koff);
        #pragma unroll
        for (int mt = 0; mt < 4; ++mt)
            #pragma unroll
            for (int nt = 0; nt < 2; ++nt)
                acc[mt][nt] = __builtin_amdgcn_mfma_f32_16x16x32_bf16(a[mt], b[nt], acc[mt][nt], 0, 0, 0);
    }
    float be[2]; int col[2];
    #pragma unroll
    for (int nt = 0; nt < 2; ++nt) {
        col[nt] = wn + nt * 16 + l15;
        be[nt] = b_eff[col[nt]];
    }
    #pragma unroll
    for (int mt = 0; mt < 4; ++mt) {
        const int rbase = m0 + mt * 16 + quad * 4;
        #pragma unroll
        for (int nt = 0; nt < 2; ++nt) {
            #pragma unroll
            for (int rg = 0; rg < 4; ++rg) {
                const int rowg = rbase + rg;
                if (rowg < nsites) {
                    out[(size_t)rowg * 128 + col[nt]] =
                        acc[mt][nt][rg] + be[nt] + feats[(size_t)rowg * 128 + col[nt]];
                }
            }
        }
    }
}

// ---------------------------------------------------------------------------
extern "C" void kernel_launch(void* const* d_in, const int* in_sizes, int n_in,
                              void* d_out, int out_size, void* d_ws, size_t ws_size,
                              hipStream_t stream) {
    const float* feats = (const float*)d_in[0];    // [N,128] f32
    const int* nb      = (const int*)d_in[1];      // [N,343] int32
    const float* dw_w  = (const float*)d_in[2];    // [343,128] f32
    const float* dw_b  = (const float*)d_in[3];    // [128]
    const float* ln_g  = (const float*)d_in[4];    // [128]
    const float* ln_b  = (const float*)d_in[5];    // [128]
    const float* w1    = (const float*)d_in[6];    // [128,512]
    const float* b1    = (const float*)d_in[7];    // [512]
    const float* grn_g = (const float*)d_in[8];    // [512]
    const float* grn_b = (const float*)d_in[9];    // [512]
    const float* w2    = (const float*)d_in[10];   // [512,128]
    const float* b2    = (const float*)d_in[11];   // [128]
    float* out = (float*)d_out;
    const int nsites = in_sizes[0] / 128;

    char* ws = (char*)d_ws;
    size_t off = 0;
    u16* xln   = (u16*)(ws + off);  off += (((size_t)nsites * 128 * 2) + 255) & ~(size_t)255;
    u16* h     = (u16*)(ws + off);  off += (((size_t)(nsites + 128) * 512 * 2) + 255) & ~(size_t)255;
    u16* featsb= (u16*)(ws + off);  off += (((size_t)nsites * 128 * 2) + 255) & ~(size_t)255;
    u16* dwwb  = (u16*)(ws + off);  off += 343 * 128 * 2 + 128;
    u16* w1t   = (u16*)(ws + off);  off += 512 * 128 * 2;
    u16* w2t   = (u16*)(ws + off);  off += 128 * 512 * 2;
    float* gx_sq = (float*)(ws + off); off += 512 * 4;
    float* scale = (float*)(ws + off); off += 512 * 4;
    float* b_eff = (float*)(ws + off); off += 128 * 4;

    hipMemsetAsync(gx_sq, 0, 512 * sizeof(float), stream);
    const int nfeat4 = nsites * 32;
    cast_feats_k<<<(nfeat4 + 255) / 256, 256, 0, stream>>>(feats, featsb, nfeat4);
    const int ndww4 = 343 * 32;
    cast_feats_k<<<(ndww4 + 255) / 256, 256, 0, stream>>>(dw_w, dwwb, ndww4);
    transpose_w1_k<<<256, 256, 0, stream>>>(w1, w1t);
    dwln_k<<<(nsites + 7) / 8, 256, 0, stream>>>(featsb, nb, dwwb, dw_b, ln_g, ln_b, xln, nsites);
    const int mblocks = (nsites + 127) / 128;
    gemm1_k<<<dim3(mblocks, 4), 256, 0, stream>>>(xln, w1t, b1, h, gx_sq, nsites);
    grn_scale_k<<<1, 512, 0, stream>>>(gx_sq, grn_g, grn_b, w2, b2, scale, b_eff);
    w2t_k<<<256, 256, 0, stream>>>(scale, w2, w2t);
    const int m2blocks = (nsites + 63) / 64;
    gemm2_k<<<m2blocks, 256, 0, stream>>>(h, w2t, b_eff, feats, out, nsites);
}

// Round 8
// 494.263 us; speedup vs baseline: 1.1817x; 1.0463x over previous
//
#include <hip/hip_runtime.h>

typedef unsigned short u16;
typedef unsigned int u32;
typedef __attribute__((ext_vector_type(8))) short bf16x8;   // 8 bf16 = 4 VGPRs (MFMA A/B frag)
typedef __attribute__((ext_vector_type(4))) float f32x4;    // MFMA C/D frag

__device__ __forceinline__ u16 f2bf(float f) {
    u32 u = __float_as_uint(f);
    return (u16)((u + 0x7FFFu + ((u >> 16) & 1u)) >> 16);   // round-to-nearest-even
}
// XOR swizzle for 128x128 bf16 tile stored as uint4[2048]: row r (0..127), 16B-chunk c (0..15)
__device__ __forceinline__ int sw_idx(int r, int c) { return r * 16 + (c ^ (r & 15)); }

// fast GELU: tanh approximation (~12 VALU inst; |err| vs exact erf-gelu ~3e-3)
__device__ __forceinline__ float fast_gelu(float x) {
    const float x3 = x * x * x;
    const float y2 = 1.5957691216057308f * (x + 0.044715f * x3);   // 2*0.79788456*(x+c x^3)
    const float u = __expf(fminf(y2, 80.f));                        // e^{2y}, overflow-capped
    const float th = (u - 1.f) / (u + 1.f);                         // tanh(y)
    return 0.5f * x * (1.f + th);
}

// ---------------------------------------------------------------------------
// Prep: cast fp32 -> bf16 streaming (feats / dw_w)
// ---------------------------------------------------------------------------
__global__ __launch_bounds__(256) void cast_feats_k(
    const float* __restrict__ src, u16* __restrict__ dst, int n4)
{
    const int e = blockIdx.x * 256 + threadIdx.x;
    if (e >= n4) return;
    const float4 v = *(const float4*)(src + (size_t)e * 4);
    uint2 o;
    o.x = (u32)f2bf(v.x) | ((u32)f2bf(v.y) << 16);
    o.y = (u32)f2bf(v.z) | ((u32)f2bf(v.w) << 16);
    *(uint2*)(dst + (size_t)e * 4) = o;
}

// ---------------------------------------------------------------------------
// Kernel A: sparse depthwise conv + bias + LayerNorm.  TWO sites per wave:
// packed dual prefix-sum compaction, interleaved gather streams.
// ---------------------------------------------------------------------------
__global__ __launch_bounds__(256) void dwln_k(
    const u16* __restrict__ featsb, const int* __restrict__ nb,
    const u16* __restrict__ dwwb, const float* __restrict__ dw_b,
    const float* __restrict__ ln_g, const float* __restrict__ ln_b,
    u16* __restrict__ xln, int nsites)
{
    __shared__ int lists[8][348];
    const int w = threadIdx.x >> 6;
    const int lane = threadIdx.x & 63;
    const int s0 = blockIdx.x * 8 + w * 2;
    if (s0 >= nsites) return;
    const bool two = (s0 + 1) < nsites;
    const int* rowA = nb + (size_t)s0 * 343;
    const int* rowB = nb + (size_t)(two ? s0 + 1 : s0) * 343;
    int idxA[6], idxB[6];
    #pragma unroll
    for (int j = 0; j < 5; ++j) {
        idxA[j] = rowA[lane + j * 64];
        const int vb = rowB[lane + j * 64];
        idxB[j] = two ? vb : nsites;
    }
    idxA[5] = (lane < 23) ? rowA[320 + lane] : nsites;
    idxB[5] = (two && lane < 23) ? rowB[320 + lane] : nsites;
    int cA = 0, cB = 0;
    #pragma unroll
    for (int i = 0; i < 6; ++i) {
        cA += (idxA[i] < nsites) ? 1 : 0;
        cB += (idxB[i] < nsites) ? 1 : 0;
    }
    const int packed = cA | (cB << 16);
    int pre = packed;
    #pragma unroll
    for (int off = 1; off < 64; off <<= 1) {
        const int v = __shfl_up(pre, off, 64);
        if (lane >= off) pre += v;
    }
    const int tot = __shfl(pre, 63, 64);
    const int cntA = tot & 0xFFFF, cntB = tot >> 16;
    pre -= packed;
    int pA = pre & 0xFFFF, pB = pre >> 16;
    #pragma unroll
    for (int i = 0; i < 6; ++i) {
        const int k = (i < 5) ? (lane + i * 64) : (320 + lane);
        if (idxA[i] < nsites) lists[w * 2][pA++] = idxA[i] | (k << 17);
        if (idxB[i] < nsites) lists[w * 2 + 1][pB++] = idxB[i] | (k << 17);
    }
    float xA0 = 0.f, xA1 = 0.f, xB0 = 0.f, xB1 = 0.f;
    const int mx = (cntA > cntB) ? cntA : cntB;
    for (int base = 0; base < mx; base += 4) {
        u32 fa[4], wa[4], fb[4], wb[4];
        #pragma unroll
        for (int i = 0; i < 4; ++i) {
            if (base + i < cntA) {
                const int p = lists[w * 2][base + i];
                fa[i] = *(const u32*)(featsb + (size_t)(p & 0x1FFFF) * 128 + lane * 2);
                wa[i] = *(const u32*)(dwwb + (size_t)(p >> 17) * 128 + lane * 2);
            } else { fa[i] = 0u; wa[i] = 0u; }
            if (base + i < cntB) {
                const int p = lists[w * 2 + 1][base + i];
                fb[i] = *(const u32*)(featsb + (size_t)(p & 0x1FFFF) * 128 + lane * 2);
                wb[i] = *(const u32*)(dwwb + (size_t)(p >> 17) * 128 + lane * 2);
            } else { fb[i] = 0u; wb[i] = 0u; }
        }
        #pragma unroll
        for (int i = 0; i < 4; ++i) {
            xA0 += __uint_as_float(fa[i] << 16) * __uint_as_float(wa[i] << 16);
            xA1 += __uint_as_float(fa[i] & 0xFFFF0000u) * __uint_as_float(wa[i] & 0xFFFF0000u);
            xB0 += __uint_as_float(fb[i] << 16) * __uint_as_float(wb[i] << 16);
            xB1 += __uint_as_float(fb[i] & 0xFFFF0000u) * __uint_as_float(wb[i] & 0xFFFF0000u);
        }
    }
    const float2 bv = *(const float2*)(dw_b + lane * 2);
    const float2 gv = *(const float2*)(ln_g + lane * 2);
    const float2 lbv = *(const float2*)(ln_b + lane * 2);
    #pragma unroll
    for (int sidx = 0; sidx < 2; ++sidx) {
        if (sidx == 1 && !two) break;
        float a0 = (sidx == 0) ? xA0 : xB0;
        float a1 = (sidx == 0) ? xA1 : xB1;
        a0 += bv.x; a1 += bv.y;
        float s = a0 + a1, ss = a0 * a0 + a1 * a1;
        #pragma unroll
        for (int off = 32; off > 0; off >>= 1) {
            s += __shfl_xor(s, off, 64);
            ss += __shfl_xor(ss, off, 64);
        }
        const float mean = s * (1.f / 128.f);
        const float var = ss * (1.f / 128.f) - mean * mean;
        const float rstd = rsqrtf(fmaxf(var, 0.f) + 1e-6f);
        const float y0 = (a0 - mean) * rstd * gv.x + lbv.x;
        const float y1 = (a1 - mean) * rstd * gv.y + lbv.y;
        *(u32*)(xln + (size_t)(s0 + sidx) * 128 + lane * 2) =
            (u32)f2bf(y0) | ((u32)f2bf(y1) << 16);
    }
}

// ---------------------------------------------------------------------------
// w1 fp32 [128,512] -> w1t bf16 [512,128] (channel-major for MFMA frag reads)
// ---------------------------------------------------------------------------
__global__ __launch_bounds__(256) void transpose_w1_k(
    const float* __restrict__ w1, u16* __restrict__ w1t)
{
    const int e = blockIdx.x * 256 + threadIdx.x;    // 65536 total
    const int n = e >> 7, k = e & 127;
    w1t[e] = f2bf(w1[k * 512 + n]);
}

// ---------------------------------------------------------------------------
// Kernel B: h = gelu(xln @ w1 + b1) [N,512] bf16 + per-channel sum(h^2).
// OPERAND-SWAPPED MFMA (A=w1t channel rows, B=xln site rows) so each lane's
// C-regs hold 4 CONSECUTIVE CHANNELS of one site -> 8-byte packed h stores
// into unchanged h[m][512] layout. Zero LDS tile, zero main-loop barriers;
// grid (4, mb) so the 4 N-blocks of an M-tile run back-to-back (xln L2-hot).
// ---------------------------------------------------------------------------
__global__ __launch_bounds__(256, 4) void gemm1_k(
    const u16* __restrict__ xln, const u16* __restrict__ w1t,
    const float* __restrict__ b1, u16* __restrict__ h,
    float* __restrict__ gx_sq, int nsites)
{
    __shared__ float s_red[128];
    const int t = threadIdx.x;
    const int n0 = blockIdx.x * 128;     // channel block
    const int m0 = blockIdx.y * 64;      // site block
    const int lane = t & 63;
    const int w = t >> 6;
    const int wn = w * 32;               // wave's 32-channel slice
    const int l15 = lane & 15, quad = lane >> 4;
    if (t < 128) s_red[t] = 0.f;
    __syncthreads();
    f32x4 acc[2][4];                     // [nt (chan 16-grp)][mt (site 16-grp)]
    #pragma unroll
    for (int i = 0; i < 2; ++i)
        #pragma unroll
        for (int j = 0; j < 4; ++j) acc[i][j] = f32x4{0.f, 0.f, 0.f, 0.f};
    const u16* a_base = w1t + (size_t)(n0 + wn + l15) * 128 + quad * 8;  // channel rows
    const u16* b_base = xln + (size_t)(m0 + l15) * 128 + quad * 8;       // site rows
    #pragma unroll
    for (int ks = 0; ks < 4; ++ks) {
        const int koff = ks * 32;
        bf16x8 a[2], b[4];
        #pragma unroll
        for (int nt = 0; nt < 2; ++nt)
            a[nt] = *(const bf16x8*)(a_base + (size_t)nt * 16 * 128 + koff);
        #pragma unroll
        for (int mt = 0; mt < 4; ++mt)
            b[mt] = *(const bf16x8*)(b_base + (size_t)mt * 16 * 128 + koff);
        #pragma unroll
        for (int nt = 0; nt < 2; ++nt)
            #pragma unroll
            for (int mt = 0; mt < 4; ++mt)
                acc[nt][mt] = __builtin_amdgcn_mfma_f32_16x16x32_bf16(a[nt], b[mt], acc[nt][mt], 0, 0, 0);
    }
    // epilogue: lane holds channels chb..chb+3 (consecutive) for site m0+mt*16+l15
    float ssl[2][4] = {{0.f,0.f,0.f,0.f},{0.f,0.f,0.f,0.f}};
    #pragma unroll
    for (int nt = 0; nt < 2; ++nt) {
        const int chb = n0 + wn + nt * 16 + quad * 4;        // global channel base
        const float4 b1v = *(const float4*)(b1 + chb);
        #pragma unroll
        for (int mt = 0; mt < 4; ++mt) {
            const int site = m0 + mt * 16 + l15;
            if (site < nsites) {
                float v[4];
                #pragma unroll
                for (int rg = 0; rg < 4; ++rg) {
                    v[rg] = fast_gelu(acc[nt][mt][rg] + ((const float*)&b1v)[rg]);
                    ssl[nt][rg] += v[rg] * v[rg];
                }
                uint2 o;
                o.x = (u32)f2bf(v[0]) | ((u32)f2bf(v[1]) << 16);
                o.y = (u32)f2bf(v[2]) | ((u32)f2bf(v[3]) << 16);
                *(uint2*)(h + (size_t)site * 512 + chb) = o;
            }
        }
    }
    // reduce ssl over the 16 l15-lanes (same channel), then 4 lanes/wave do LDS atomics
    #pragma unroll
    for (int nt = 0; nt < 2; ++nt)
        #pragma unroll
        for (int rg = 0; rg < 4; ++rg) {
            float v = ssl[nt][rg];
            v += __shfl_xor(v, 1, 64);
            v += __shfl_xor(v, 2, 64);
            v += __shfl_xor(v, 4, 64);
            v += __shfl_xor(v, 8, 64);
            if (l15 == 0) atomicAdd(&s_red[wn + nt * 16 + quad * 4 + rg], v);
        }
    __syncthreads();
    if (t < 128) atomicAdd(&gx_sq[n0 + t], s_red[t]);
}

// ---------------------------------------------------------------------------
// Kernel C1: GRN scale + effective bias (one block, cooperative).
// ---------------------------------------------------------------------------
__global__ __launch_bounds__(512) void grn_scale_k(
    const float* __restrict__ gx_sq, const float* __restrict__ grn_g,
    const float* __restrict__ grn_b, const float* __restrict__ w2,
    const float* __restrict__ b2, float* __restrict__ scale, float* __restrict__ b_eff)
{
    __shared__ float red[512];
    __shared__ float redb[512];
    const int t = threadIdx.x;
    const float g = sqrtf(gx_sq[t]);
    red[t] = g;
    __syncthreads();
    #pragma unroll
    for (int off = 256; off > 0; off >>= 1) {
        if (t < off) red[t] += red[t + off];
        __syncthreads();
    }
    const float mean = red[0] * (1.f / 512.f);
    scale[t] = grn_g[t] * (g / (mean + 1e-6f)) + 1.f;
    const int dc = t & 127, grp = t >> 7;
    float p = 0.f;
    #pragma unroll 8
    for (int i = 0; i < 128; ++i) {
        const int c = grp * 128 + i;
        p += grn_b[c] * w2[(size_t)c * 128 + dc];
    }
    redb[t] = p;
    __syncthreads();
    if (t < 128) b_eff[t] = b2[t] + redb[t] + redb[t + 128] + redb[t + 256] + redb[t + 384];
}

// ---------------------------------------------------------------------------
// Kernel C2: w2t[dc][c] = bf16(scale[c] * w2[c][dc])  (coalesced writes)
// ---------------------------------------------------------------------------
__global__ __launch_bounds__(256) void w2t_k(
    const float* __restrict__ scale, const float* __restrict__ w2,
    u16* __restrict__ w2t)
{
    const int e = blockIdx.x * 256 + threadIdx.x;    // 65536
    const int c = e & 511, dc = e >> 9;
    w2t[e] = f2bf(scale[c] * w2[(size_t)c * 128 + dc]);
}

// ---------------------------------------------------------------------------
// Kernel D: out = feats + h_scaled @ w2 + b_eff (fp32 out).
// M-tile 64, NO LDS/barriers, K=512 fully unrolled; A streams h, B L2-hot.
// ---------------------------------------------------------------------------
__global__ __launch_bounds__(256, 4) void gemm2_k(
    const u16* __restrict__ h, const u16* __restrict__ w2t,
    const float* __restrict__ b_eff, const float* __restrict__ feats,
    float* __restrict__ out, int nsites)
{
    const int t = threadIdx.x;
    const int m0 = blockIdx.x * 64;
    const int lane = t & 63;
    const int w = t >> 6;
    const int wn = w * 32;
    const int l15 = lane & 15, quad = lane >> 4;
    f32x4 acc[4][2];
    #pragma unroll
    for (int i = 0; i < 4; ++i)
        #pragma unroll
        for (int j = 0; j < 2; ++j) acc[i][j] = f32x4{0.f, 0.f, 0.f, 0.f};
    const u16* a_base = h + (size_t)(m0 + l15) * 512 + quad * 8;
    const u16* b_base = w2t + (size_t)(wn + l15) * 512 + quad * 8;
    #pragma unroll
    for (int ks = 0; ks < 16; ++ks) {
        const int koff = ks * 32;
        bf16x8 a[4], b[2];
        #pragma unroll
        for (int mt = 0; mt < 4; ++mt)
            a[mt] = *(const bf16x8*)(a_base + (size_t)mt * 16 * 512 + koff);
        #pragma unroll
        for (int nt = 0; nt < 2; ++nt)
            b[nt] = *(const bf16x8*)(b_base + (size_t)nt * 16 * 512 + koff);
        #pragma unroll
        for (int mt = 0; mt < 4; ++mt)
            #pragma unroll
            for (int nt = 0; nt < 2; ++nt)
                acc[mt][nt] = __builtin_amdgcn_mfma_f32_16x16x32_bf16(a[mt], b[nt], acc[mt][nt], 0, 0, 0);
    }
    float be[2]; int col[2];
    #pragma unroll
    for (int nt = 0; nt < 2; ++nt) {
        col[nt] = wn + nt * 16 + l15;
        be[nt] = b_eff[col[nt]];
    }
    #pragma unroll
    for (int mt = 0; mt < 4; ++mt) {
        const int rbase = m0 + mt * 16 + quad * 4;
        #pragma unroll
        for (int nt = 0; nt < 2; ++nt) {
            #pragma unroll
            for (int rg = 0; rg < 4; ++rg) {
                const int rowg = rbase + rg;
                if (rowg < nsites) {
                    out[(size_t)rowg * 128 + col[nt]] =
                        acc[mt][nt][rg] + be[nt] + feats[(size_t)rowg * 128 + col[nt]];
                }
            }
        }
    }
}

// ---------------------------------------------------------------------------
extern "C" void kernel_launch(void* const* d_in, const int* in_sizes, int n_in,
                              void* d_out, int out_size, void* d_ws, size_t ws_size,
                              hipStream_t stream) {
    const float* feats = (const float*)d_in[0];    // [N,128] f32
    const int* nb      = (const int*)d_in[1];      // [N,343] int32
    const float* dw_w  = (const float*)d_in[2];    // [343,128] f32
    const float* dw_b  = (const float*)d_in[3];    // [128]
    const float* ln_g  = (const float*)d_in[4];    // [128]
    const float* ln_b  = (const float*)d_in[5];    // [128]
    const float* w1    = (const float*)d_in[6];    // [128,512]
    const float* b1    = (const float*)d_in[7];    // [512]
    const float* grn_g = (const float*)d_in[8];    // [512]
    const float* grn_b = (const float*)d_in[9];    // [512]
    const float* w2    = (const float*)d_in[10];   // [512,128]
    const float* b2    = (const float*)d_in[11];   // [128]
    float* out = (float*)d_out;
    const int nsites = in_sizes[0] / 128;

    char* ws = (char*)d_ws;
    size_t off = 0;
    u16* xln   = (u16*)(ws + off);  off += (((size_t)(nsites + 128) * 128 * 2) + 255) & ~(size_t)255;
    u16* h     = (u16*)(ws + off);  off += (((size_t)(nsites + 128) * 512 * 2) + 255) & ~(size_t)255;
    u16* featsb= (u16*)(ws + off);  off += (((size_t)nsites * 128 * 2) + 255) & ~(size_t)255;
    u16* dwwb  = (u16*)(ws + off);  off += 343 * 128 * 2 + 128;
    u16* w1t   = (u16*)(ws + off);  off += 512 * 128 * 2;
    u16* w2t   = (u16*)(ws + off);  off += 128 * 512 * 2;
    float* gx_sq = (float*)(ws + off); off += 512 * 4;
    float* scale = (float*)(ws + off); off += 512 * 4;
    float* b_eff = (float*)(ws + off); off += 128 * 4;

    hipMemsetAsync(gx_sq, 0, 512 * sizeof(float), stream);
    const int nfeat4 = nsites * 32;
    cast_feats_k<<<(nfeat4 + 255) / 256, 256, 0, stream>>>(feats, featsb, nfeat4);
    const int ndww4 = 343 * 32;
    cast_feats_k<<<(ndww4 + 255) / 256, 256, 0, stream>>>(dw_w, dwwb, ndww4);
    transpose_w1_k<<<256, 256, 0, stream>>>(w1, w1t);
    dwln_k<<<(nsites + 7) / 8, 256, 0, stream>>>(featsb, nb, dwwb, dw_b, ln_g, ln_b, xln, nsites);
    const int m1blocks = (nsites + 63) / 64;
    gemm1_k<<<dim3(4, m1blocks), 256, 0, stream>>>(xln, w1t, b1, h, gx_sq, nsites);
    grn_scale_k<<<1, 512, 0, stream>>>(gx_sq, grn_g, grn_b, w2, b2, scale, b_eff);
    w2t_k<<<256, 256, 0, stream>>>(scale, w2, w2t);
    const int m2blocks = (nsites + 63) / 64;
    gemm2_k<<<m2blocks, 256, 0, stream>>>(h, w2t, b_eff, feats, out, nsites);
}